// Round 2
// baseline (3224.512 us; speedup 1.0000x reference)
//
#include <hip/hip_runtime.h>
#include <cmath>

typedef unsigned int u32;
typedef unsigned long long u64;

#define NCAND 4507
#define WORDS 71              // ceil(4507/64)
#define ROWS_AL (WORDS * 64)  // 4544
#define TOTS 159882           // total scores across levels

__constant__ int c_W[5]      = {200, 100, 50, 25, 13};
__constant__ int c_stride[5] = {4, 8, 16, 32, 61};
__constant__ int c_Nl[5]     = {120000, 30000, 7500, 1875, 507};
__constant__ int c_soff[5]   = {0, 120000, 150000, 157500, 159375};
__constant__ int c_k[5]      = {1000, 1000, 1000, 1000, 507};

// unified conv grid: tiles per level (8x8 px tiles): 625,169,49,16,4
__constant__ int cv_boff[6]  = {0, 625, 794, 843, 859, 863};

struct DecParams { float b[5][3][4]; };
struct FeatPtrs { const float* p[5]; };

__device__ __forceinline__ u32 flipf(float f) {
    u32 u = __float_as_uint(f);
    return (u & 0x80000000u) ? ~u : (u | 0x80000000u);
}

// ---------------- workspace layout ----------------
constexpr size_t AL(size_t x) { return (x + 255) & ~(size_t)255; }
constexpr size_t OFF_WT     = 0;                                   // 589824 f
constexpr size_t OFF_HEADW  = AL(OFF_WT + 589824 * 4);             // 15*256 f
constexpr size_t OFF_HEADB  = AL(OFF_HEADW + 3840 * 4);            // 15 f
constexpr size_t OFF_SCORES = AL(OFF_HEADB + 64);                  // TOTS f
constexpr size_t OFF_DELTAS = AL(OFF_SCORES + (size_t)TOTS * 4);   // TOTS*4 f
constexpr size_t OFF_KEY    = AL(OFF_DELTAS + (size_t)TOTS * 16);  // NCAND u64
constexpr size_t OFF_SBOX   = AL(OFF_KEY + (size_t)NCAND * 8);     // NCAND*4 f
constexpr size_t OFF_SOB    = AL(OFF_SBOX + (size_t)NCAND * 16);   // NCAND*4 f
constexpr size_t OFF_SVAL   = AL(OFF_SOB + (size_t)NCAND * 16);    // NCAND u32
constexpr size_t OFF_MASK   = AL(OFF_SVAL + (size_t)NCAND * 4);    // ROWS_AL*WORDS u64
constexpr size_t OFF_KEEP   = AL(OFF_MASK + (size_t)ROWS_AL * WORDS * 8); // WORDS u64

// ---------------- kernel 1: weight prep ----------------
// wT[ci][ky][kx][co]  from conv_w[co][ci][ky][kx]; combined head weights/bias.
__global__ __launch_bounds__(256) void k_prep(
    const float* __restrict__ cw, const float* __restrict__ clsw,
    const float* __restrict__ clsb, const float* __restrict__ bw,
    const float* __restrict__ bb, float* __restrict__ wT,
    float* __restrict__ headw, float* __restrict__ headb) {
    int i = blockIdx.x * 256 + threadIdx.x;
    if (i < 589824) {
        int co = i & 255, r = i >> 8;
        int kx = r % 3, ky = (r / 3) % 3, ci = r / 9;
        wT[i] = cw[(((co << 8) + ci) * 3 + ky) * 3 + kx];
    }
    if (i < 3840) {
        int h = i >> 8, ci = i & 255;
        headw[i] = (h < 3) ? clsw[h * 256 + ci] : bw[(h - 3) * 256 + ci];
    }
    if (i < 15) headb[i] = (i < 3) ? clsb[i] : bb[i - 3];
}

// ---------------- kernel 2: fused conv3x3+ReLU + 1x1 heads, ALL LEVELS ----------------
// Block: 256 threads -> 8x8 pixel tile, all 256 output channels.
// Thread (cg,pg): 8 co x 8 px (one tile row) register micro-tile.
// Heads computed from accumulator registers via deterministic 2-stage LDS reduce
// (3 heads per chunk) -> LDS stays at 38.5 KB -> 4 blocks/CU.
__global__ __launch_bounds__(256, 4) void k_conv(
    FeatPtrs fp, const float* __restrict__ wT,
    const float* __restrict__ convb, const float* __restrict__ headw,
    const float* __restrict__ headb, float* __restrict__ scores,
    float* __restrict__ deltas) {
    __shared__ float sm[9616];  // conv: patch[4][10][10] @0, w[9216] @400; head: part[32][196]
    const int tid = threadIdx.x;
    const int cg = tid >> 3, pg = tid & 7, co0 = cg << 3;

    // level lookup
    const int bid = blockIdx.x;
    int l = 0;
#pragma unroll
    for (int q = 1; q < 5; q++) if (bid >= cv_boff[q]) l = q;
    const int H = c_W[l], W = H;
    const int soff = c_soff[l];
    const float* __restrict__ in = fp.p[l];
    const int t = bid - cv_boff[l];
    const int tilesx = (W + 7) >> 3;
    const int tx = t % tilesx, ty = t / tilesx;
    const int x0 = tx * 8, y0 = ty * 8;
    const int HW = H * W;

    float acc[8][8];
#pragma unroll
    for (int r = 0; r < 8; r++)
#pragma unroll
        for (int c = 0; c < 8; c++) acc[r][c] = 0.f;

    for (int cc0 = 0; cc0 < 256; cc0 += 4) {
        __syncthreads();
        for (int e = tid; e < 400; e += 256) {
            int ci = e / 100, rr = e % 100, py = rr / 10, px = rr % 10;
            int gy = y0 - 1 + py, gx = x0 - 1 + px;
            float v = 0.f;
            if (gy >= 0 && gy < H && gx >= 0 && gx < W)
                v = in[(cc0 + ci) * HW + gy * W + gx];
            sm[e] = v;
        }
        const float* wsrc = wT + (size_t)cc0 * 2304;
        for (int e = tid; e < 9216; e += 256) sm[400 + e] = wsrc[e];
        __syncthreads();
#pragma unroll
        for (int ci = 0; ci < 4; ci++) {
#pragma unroll
            for (int ky = 0; ky < 3; ky++) {
                float in10[10];
                int prow = (ci * 10 + pg + ky) * 10;
#pragma unroll
                for (int q = 0; q < 10; q++) in10[q] = sm[prow + q];
#pragma unroll
                for (int kx = 0; kx < 3; kx++) {
                    float w8[8];
                    int wb = 400 + ((ci * 3 + ky) * 3 + kx) * 256 + co0;
#pragma unroll
                    for (int r = 0; r < 8; r++) w8[r] = sm[wb + r];
#pragma unroll
                    for (int r = 0; r < 8; r++)
#pragma unroll
                        for (int c = 0; c < 8; c++)
                            acc[r][c] = fmaf(w8[r], in10[c + kx], acc[r][c]);
                }
            }
        }
    }
    // bias + relu in registers: acc becomes t
    {
        float bias[8];
#pragma unroll
        for (int r = 0; r < 8; r++) bias[r] = convb[co0 + r];
#pragma unroll
        for (int r = 0; r < 8; r++)
#pragma unroll
            for (int c = 0; c < 8; c++) {
                float tv = acc[r][c] + bias[r];
                acc[r][c] = tv > 0.f ? tv : 0.f;
            }
    }
    // heads: 15 heads in chunks of 3; per-thread partial over its 8 co,
    // then deterministic 32-way tree over cg in LDS. part layout: [cg][px*3+h'] pad 196.
    for (int hc = 0; hc < 15; hc += 3) {
        float hw3[3][8];
#pragma unroll
        for (int h3 = 0; h3 < 3; h3++)
#pragma unroll
            for (int r = 0; r < 8; r++)
                hw3[h3][r] = headw[(hc + h3) * 256 + co0 + r];
        float part[3][8];
#pragma unroll
        for (int h3 = 0; h3 < 3; h3++)
#pragma unroll
            for (int c = 0; c < 8; c++) part[h3][c] = 0.f;
#pragma unroll
        for (int r = 0; r < 8; r++)
#pragma unroll
            for (int c = 0; c < 8; c++) {
                float tv = acc[r][c];
#pragma unroll
                for (int h3 = 0; h3 < 3; h3++)
                    part[h3][c] = fmaf(hw3[h3][r], tv, part[h3][c]);
            }
        __syncthreads();  // previous chunk's reads (or conv phase) done
        int base = cg * 196 + pg * 24;
#pragma unroll
        for (int c = 0; c < 8; c++)
#pragma unroll
            for (int h3 = 0; h3 < 3; h3++)
                sm[base + c * 3 + h3] = part[h3][c];
        __syncthreads();
        if (tid < 192) {
            int px = tid / 3, h3 = tid % 3;
            int h = hc + h3;
            float sum = 0.f;
#pragma unroll
            for (int g = 0; g < 32; g++) sum += sm[g * 196 + tid];
            sum += headb[h];
            int row = px >> 3, col = px & 7;
            int gy = y0 + row, gx = x0 + col;
            if (gy < H && gx < W) {
                int pix = gy * W + gx;
                if (h < 3) {
                    scores[soff + pix * 3 + h] = sum;
                } else {
                    int ch = h - 3;
                    deltas[((size_t)(soff + pix * 3 + (ch >> 2))) * 4 + (ch & 3)] = sum;
                }
            }
        }
    }
}

// ---------------- kernel 3: per-level exact top-k (radix select) ----------------
// Writes sort keys directly: key = (~flip(score) << 32) | (level<<24 | idx)
__global__ __launch_bounds__(1024) void k_topk(
    const float* __restrict__ scores, u64* __restrict__ key) {
    const int l = blockIdx.x;
    const int Nl = c_Nl[l], off = c_soff[l], k = c_k[l];
    const int base = l * 1000;
    const int tid = threadIdx.x;
    const u32 lshift = (u32)l << 24;
    __shared__ u32 hist[256];
    __shared__ u32 sh_prefix, sh_m, sh_sel, sh_tie;
    __shared__ u32 tiebuf[2048];
    if (tid == 0) { sh_sel = 0; sh_tie = 0; }
    __syncthreads();

    if (k == Nl) {  // take everything (level 4)
        for (int i = tid; i < Nl; i += 1024) {
            u32 p = atomicAdd(&sh_sel, 1u);
            u32 k32 = flipf(scores[off + i]);
            key[base + p] = ((u64)(~k32) << 32) | (u64)(lshift | (u32)i);
        }
        return;
    }
    u32 prefix = 0, m = (u32)k;
    for (int p = 0; p < 4; p++) {
        int shift = 24 - 8 * p;
        for (int b = tid; b < 256; b += 1024) hist[b] = 0;
        __syncthreads();
        for (int i = tid; i < Nl; i += 1024) {
            u32 k32 = flipf(scores[off + i]);
            if (p == 0 || (k32 >> (shift + 8)) == prefix)
                atomicAdd(&hist[(k32 >> shift) & 255u], 1u);
        }
        __syncthreads();
        if (tid == 0) {
            u32 cum = 0;
            for (int b = 255; b >= 0; --b) {
                u32 c = hist[b];
                if (cum + c >= m) { sh_prefix = (prefix << 8) | (u32)b; sh_m = m - cum; break; }
                cum += c;
            }
        }
        __syncthreads();
        prefix = sh_prefix; m = sh_m;
        __syncthreads();
    }
    // compact: strictly greater -> selected; equal -> tie list
    for (int i = tid; i < Nl; i += 1024) {
        u32 k32 = flipf(scores[off + i]);
        if (k32 > prefix) {
            u32 p = atomicAdd(&sh_sel, 1u);
            key[base + p] = ((u64)(~k32) << 32) | (u64)(lshift | (u32)i);
        } else if (k32 == prefix) {
            u32 t = atomicAdd(&sh_tie, 1u);
            if (t < 2048u) tiebuf[t] = (u32)i;
        }
    }
    __syncthreads();
    u32 nsel = sh_sel;
    u32 ntie = sh_tie; if (ntie > 2048u) ntie = 2048u;
    if (ntie != m) {  // need m smallest indices among ties
        for (u32 j = tid; j < 2048; j += 1024) if (j >= ntie) tiebuf[j] = 0xFFFFFFFFu;
        __syncthreads();
        for (u32 ksz = 2; ksz <= 2048; ksz <<= 1) {
            for (u32 jj = ksz >> 1; jj > 0; jj >>= 1) {
                for (u32 i2 = tid; i2 < 2048; i2 += 1024) {
                    u32 ixj = i2 ^ jj;
                    if (ixj > i2) {
                        u32 a = tiebuf[i2], b = tiebuf[ixj];
                        bool up = ((i2 & ksz) == 0);
                        if ((a > b) == up) { tiebuf[i2] = b; tiebuf[ixj] = a; }
                    }
                }
                __syncthreads();
            }
        }
    }
    for (u32 j = tid; j < m; j += 1024)
        key[base + nsel + j] = ((u64)(~prefix) << 32) | (u64)(lshift | tiebuf[j]);
}

// ---------------- kernel 4: global bitonic sort + inline decode ----------------
__global__ __launch_bounds__(1024) void k_sort(
    const u64* __restrict__ key, const float* __restrict__ deltas, DecParams P,
    float* __restrict__ sboxes, float* __restrict__ sob, u32* __restrict__ svalid) {
    __shared__ u64 sk[8192];
    const int tid = threadIdx.x;
    for (int i = tid; i < 8192; i += 1024) sk[i] = (i < NCAND) ? key[i] : ~0ull;
    __syncthreads();
    for (u32 ksz = 2; ksz <= 8192; ksz <<= 1) {
        for (u32 j = ksz >> 1; j > 0; j >>= 1) {
            for (u32 i = tid; i < 8192; i += 1024) {
                u32 ixj = i ^ j;
                if (ixj > i) {
                    u64 a = sk[i], b = sk[ixj];
                    bool up = ((i & ksz) == 0);
                    if ((a > b) == up) { sk[i] = b; sk[ixj] = a; }
                }
            }
            __syncthreads();
        }
    }
    const float CLAMP = 4.135166556742356f;  // log(1000/16)
    for (int s = tid; s < NCAND; s += 1024) {
        u32 info = (u32)sk[s];
        int l = info >> 24, idx = info & 0xFFFFFF;
        int W = c_W[l], st = c_stride[l];
        int a = idx % 3, pix = idx / 3;
        int x = pix % W, y = pix / W;
        float ax1 = x * st + P.b[l][a][0];
        float ay1 = y * st + P.b[l][a][1];
        float ax2 = x * st + P.b[l][a][2];
        float ay2 = y * st + P.b[l][a][3];
        float w_ = ax2 - ax1, h_ = ay2 - ay1;
        float cx = ax1 + 0.5f * w_, cy = ay1 + 0.5f * h_;
        const float* d = deltas + ((size_t)(c_soff[l] + idx)) * 4;
        float dx = d[0], dy = d[1];
        float dw = fminf(d[2], CLAMP), dh = fminf(d[3], CLAMP);
        float pcx = dx * w_ + cx, pcy = dy * h_ + cy;
        float pw = expf(dw) * w_, ph = expf(dh) * h_;
        float x1 = pcx - 0.5f * pw, y1 = pcy - 0.5f * ph;
        float x2 = pcx + 0.5f * pw, y2 = pcy + 0.5f * ph;
        x1 = fminf(fmaxf(x1, 0.f), 800.f); y1 = fminf(fmaxf(y1, 0.f), 800.f);
        x2 = fminf(fmaxf(x2, 0.f), 800.f); y2 = fminf(fmaxf(y2, 0.f), 800.f);
        u32 vv = (x2 - x1 >= 0.001f && y2 - y1 >= 0.001f) ? 1u : 0u;
        float offv = (float)l * 801.0f;
        sboxes[s * 4 + 0] = x1; sboxes[s * 4 + 1] = y1;
        sboxes[s * 4 + 2] = x2; sboxes[s * 4 + 3] = y2;
        sob[s * 4 + 0] = x1 + offv; sob[s * 4 + 1] = y1 + offv;
        sob[s * 4 + 2] = x2 + offv; sob[s * 4 + 3] = y2 + offv;
        svalid[s] = vv;
    }
}

// ---------------- kernel 5: IoU suppression bitmask ----------------
__global__ __launch_bounds__(256) void k_mask(
    const float* __restrict__ sob, u64* __restrict__ mask) {
    int gid = blockIdx.x * 256 + threadIdx.x;
    const int total = NCAND * WORDS;
    if (gid >= total) return;
    int i = gid / WORDS, w = gid - i * WORDS;
    float bx1 = sob[i * 4], by1 = sob[i * 4 + 1], bx2 = sob[i * 4 + 2], by2 = sob[i * 4 + 3];
    float ai = (bx2 - bx1) * (by2 - by1);
    u64 bits = 0;
    int j0 = w * 64;
    for (int b = 0; b < 64; b++) {
        int j = j0 + b;
        if (j < NCAND && j > i) {
            float cx1 = sob[j * 4], cy1 = sob[j * 4 + 1], cx2 = sob[j * 4 + 2], cy2 = sob[j * 4 + 3];
            float lt0 = fmaxf(bx1, cx1), lt1 = fmaxf(by1, cy1);
            float rb0 = fminf(bx2, cx2), rb1 = fminf(by2, cy2);
            float ww = fmaxf(rb0 - lt0, 0.f), hh = fmaxf(rb1 - lt1, 0.f);
            float inter = ww * hh;
            float aj = (cx2 - cx1) * (cy2 - cy1);
            float u = ai + aj - inter;
            float iou = inter / u;           // 0/0 -> NaN -> no suppression (matches ref)
            if (iou > 0.7f) bits |= (1ull << b);
        }
    }
    mask[(size_t)i * WORDS + w] = bits;
}

// ---------------- kernel 6: tiled greedy NMS scan (single block) ----------------
__global__ __launch_bounds__(256) void k_scan(
    const u64* __restrict__ mask, const u32* __restrict__ svalid,
    u64* __restrict__ keepg) {
    __shared__ u64 keep[WORDS];
    __shared__ u32 ormL[WORDS], ormH[WORDS];
    const int tid = threadIdx.x;
    if (tid < WORDS) {
        u64 w0 = 0;
        for (int b = 0; b < 64; b++) {
            int idx = tid * 64 + b;
            if (idx < NCAND && svalid[idx]) w0 |= (1ull << b);
        }
        keep[tid] = w0; ormL[tid] = 0; ormH[tid] = 0;
    }
    __syncthreads();
    for (int t = 0; t < WORDS; t++) {
        if (tid < 64) {  // wave 0: serial intra-tile resolve on the diagonal word
            int row = t * 64 + tid;
            u64 d = (row < NCAND) ? mask[(size_t)row * WORDS + t] : 0ull;
            u32 dlo = (u32)d, dhi = (u32)(d >> 32);
            u64 cur = keep[t];
            u64 pending = cur;
            while (pending) {
                int b = __builtin_ctzll(pending);
                pending &= pending - 1;
                u64 mb = ((u64)__shfl(dhi, b, 64) << 32) | (u64)__shfl(dlo, b, 64);
                cur &= ~mb;       // row b is alive (pending only holds survivors)
                pending &= ~mb;   // skip rows it just suppressed
            }
            if (tid == 0) keep[t] = cur;
        }
        __syncthreads();
        u64 kw = keep[t];
        int nW = WORDS - 1 - t;
        for (int task = tid; task < 64 * nW; task += 256) {
            int r = task / nW, w = t + 1 + (task - r * nW);
            if ((kw >> r) & 1ull) {
                u64 mrow = mask[(size_t)(t * 64 + r) * WORDS + w];
                if (mrow) {
                    atomicOr(&ormL[w], (u32)mrow);
                    atomicOr(&ormH[w], (u32)(mrow >> 32));
                }
            }
        }
        __syncthreads();
        if (tid > t && tid < WORDS) {
            keep[tid] &= ~(((u64)ormH[tid] << 32) | (u64)ormL[tid]);
            ormL[tid] = 0; ormH[tid] = 0;
        }
        __syncthreads();
    }
    if (tid < WORDS) keepg[tid] = keep[tid];
}

// ---------------- kernel 7: final gather (kept first, then -inf pads) ----------------
__global__ __launch_bounds__(1024) void k_out(
    const u64* __restrict__ keepg, const float* __restrict__ sboxes,
    float* __restrict__ out) {
    __shared__ u32 sc[1024];
    __shared__ u64 kw[WORDS];
    const int tid = threadIdx.x;
    if (tid < WORDS) kw[tid] = keepg[tid];
    __syncthreads();
    const int i0 = tid * 5;
    u32 cnt = 0;
    for (int e = 0; e < 5; e++) {
        int i = i0 + e;
        if (i < NCAND) cnt += (u32)((kw[i >> 6] >> (i & 63)) & 1ull);
    }
    sc[tid] = cnt;
    __syncthreads();
    for (int off = 1; off < 1024; off <<= 1) {
        u32 v = (tid >= off) ? sc[tid - off] : 0;
        __syncthreads();
        sc[tid] += v;
        __syncthreads();
    }
    u32 incl = sc[tid];
    u32 total = sc[1023];
    u32 kr = incl - cnt;  // kept before my first element
    for (int e = 0; e < 5; e++) {
        int i = i0 + e;
        if (i < NCAND) {
            bool kp = (kw[i >> 6] >> (i & 63)) & 1ull;
            if (kp) {
                if (kr < 1000u) {
                    out[kr * 4 + 0] = sboxes[i * 4 + 0];
                    out[kr * 4 + 1] = sboxes[i * 4 + 1];
                    out[kr * 4 + 2] = sboxes[i * 4 + 2];
                    out[kr * 4 + 3] = sboxes[i * 4 + 3];
                }
                kr++;
            } else {
                u32 slot = total + (u32)i - kr;
                if (slot < 1000u) {
                    out[slot * 4 + 0] = sboxes[i * 4 + 0];
                    out[slot * 4 + 1] = sboxes[i * 4 + 1];
                    out[slot * 4 + 2] = sboxes[i * 4 + 2];
                    out[slot * 4 + 3] = sboxes[i * 4 + 3];
                }
            }
        }
    }
}

// ---------------- host ----------------
extern "C" void kernel_launch(void* const* d_in, const int* in_sizes, int n_in,
                              void* d_out, int out_size, void* d_ws, size_t ws_size,
                              hipStream_t stream) {
    (void)in_sizes; (void)n_in; (void)out_size; (void)ws_size;
    FeatPtrs fp;
    for (int i = 0; i < 5; i++) fp.p[i] = (const float*)d_in[i];
    const float* conv_w = (const float*)d_in[5];
    const float* conv_b = (const float*)d_in[6];
    const float* cls_w  = (const float*)d_in[7];
    const float* cls_b  = (const float*)d_in[8];
    const float* bbox_w = (const float*)d_in[9];
    const float* bbox_b = (const float*)d_in[10];

    char* ws = (char*)d_ws;
    float* wT     = (float*)(ws + OFF_WT);
    float* headw  = (float*)(ws + OFF_HEADW);
    float* headb  = (float*)(ws + OFF_HEADB);
    float* scores = (float*)(ws + OFF_SCORES);
    float* deltas = (float*)(ws + OFF_DELTAS);
    u64*   key    = (u64*)(ws + OFF_KEY);
    float* sboxes = (float*)(ws + OFF_SBOX);
    float* sob    = (float*)(ws + OFF_SOB);
    u32*   svalid = (u32*)(ws + OFF_SVAL);
    u64*   maskp  = (u64*)(ws + OFF_MASK);
    u64*   keepg  = (u64*)(ws + OFF_KEEP);

    k_prep<<<2304, 256, 0, stream>>>(conv_w, cls_w, cls_b, bbox_w, bbox_b, wT, headw, headb);

    // one launch for all 5 levels: 625+169+49+16+4 = 863 tiles
    k_conv<<<863, 256, 0, stream>>>(fp, wT, conv_b, headw, headb, scores, deltas);

    k_topk<<<5, 1024, 0, stream>>>(scores, key);

    DecParams dp;
    {
        const double sz[5] = {32.0, 64.0, 128.0, 256.0, 512.0};
        const double rt[3] = {0.5, 1.0, 2.0};
        for (int l = 0; l < 5; l++)
            for (int a = 0; a < 3; a++) {
                double hr = sqrt(rt[a]);
                double wr = 1.0 / hr;
                double w = wr * sz[l], h = hr * sz[l];
                dp.b[l][a][0] = (float)nearbyint(-w / 2.0);
                dp.b[l][a][1] = (float)nearbyint(-h / 2.0);
                dp.b[l][a][2] = (float)nearbyint(w / 2.0);
                dp.b[l][a][3] = (float)nearbyint(h / 2.0);
            }
    }
    k_sort<<<1, 1024, 0, stream>>>(key, deltas, dp, sboxes, sob, svalid);
    k_mask<<<(NCAND * WORDS + 255) / 256, 256, 0, stream>>>(sob, maskp);
    k_scan<<<1, 256, 0, stream>>>(maskp, svalid, keepg);
    k_out<<<1, 1024, 0, stream>>>(keepg, sboxes, (float*)d_out);
}

// Round 3
// 2404.656 us; speedup vs baseline: 1.3409x; 1.3409x over previous
//
#include <hip/hip_runtime.h>
#include <cmath>

typedef unsigned int u32;
typedef unsigned long long u64;

#define NCAND 4507
#define WORDS 71              // ceil(4507/64)
#define ROWS_AL (WORDS * 64)  // 4544
#define TOTS 159882           // total scores across levels

__constant__ int c_W[5]      = {200, 100, 50, 25, 13};
__constant__ int c_stride[5] = {4, 8, 16, 32, 61};
__constant__ int c_Nl[5]     = {120000, 30000, 7500, 1875, 507};
__constant__ int c_soff[5]   = {0, 120000, 150000, 157500, 159375};
__constant__ int c_k[5]      = {1000, 1000, 1000, 1000, 507};

// unified conv grid: tiles per level (8x8 px tiles): 625,169,49,16,4
__constant__ int cv_boff[6]  = {0, 625, 794, 843, 859, 863};

struct DecParams { float b[5][3][4]; };
struct FeatPtrs { const float* p[5]; };

__device__ __forceinline__ u32 flipf(float f) {
    u32 u = __float_as_uint(f);
    return (u & 0x80000000u) ? ~u : (u | 0x80000000u);
}

// ---------------- workspace layout ----------------
constexpr size_t AL(size_t x) { return (x + 255) & ~(size_t)255; }
constexpr size_t OFF_WT     = 0;                                   // 589824 f
constexpr size_t OFF_HEADW  = AL(OFF_WT + 589824 * 4);             // 15*256 f
constexpr size_t OFF_HEADB  = AL(OFF_HEADW + 3840 * 4);            // 15 f
constexpr size_t OFF_SCORES = AL(OFF_HEADB + 64);                  // TOTS f
constexpr size_t OFF_DELTAS = AL(OFF_SCORES + (size_t)TOTS * 4);   // TOTS*4 f
constexpr size_t OFF_KEY    = AL(OFF_DELTAS + (size_t)TOTS * 16);  // NCAND u64
constexpr size_t OFF_SBOX   = AL(OFF_KEY + (size_t)NCAND * 8);     // NCAND*4 f
constexpr size_t OFF_SOB    = AL(OFF_SBOX + (size_t)NCAND * 16);   // NCAND*4 f
constexpr size_t OFF_SVAL   = AL(OFF_SOB + (size_t)NCAND * 16);    // NCAND u32
constexpr size_t OFF_MASK   = AL(OFF_SVAL + (size_t)NCAND * 4);    // ROWS_AL*WORDS u64
constexpr size_t OFF_KEEP   = AL(OFF_MASK + (size_t)ROWS_AL * WORDS * 8); // WORDS u64

// ---------------- kernel 1: weight prep ----------------
// wT[ci][ky][kx][co]  from conv_w[co][ci][ky][kx]; combined head weights/bias.
__global__ __launch_bounds__(256) void k_prep(
    const float* __restrict__ cw, const float* __restrict__ clsw,
    const float* __restrict__ clsb, const float* __restrict__ bw,
    const float* __restrict__ bb, float* __restrict__ wT,
    float* __restrict__ headw, float* __restrict__ headb) {
    int i = blockIdx.x * 256 + threadIdx.x;
    if (i < 589824) {
        int co = i & 255, r = i >> 8;
        int kx = r % 3, ky = (r / 3) % 3, ci = r / 9;
        wT[i] = cw[(((co << 8) + ci) * 3 + ky) * 3 + kx];
    }
    if (i < 3840) {
        int h = i >> 8, ci = i & 255;
        headw[i] = (h < 3) ? clsw[h * 256 + ci] : bw[(h - 3) * 256 + ci];
    }
    if (i < 15) headb[i] = (i < 3) ? clsb[i] : bb[i - 3];
}

// ---------------- kernel 2: fused conv3x3+ReLU + 1x1 heads, ALL LEVELS ----------------
// Block: 256 threads -> 8x8 pixel tile, all 256 output channels.
// Thread (cg,pg): 8 co x 8 px register micro-tile.
// LDS: single 38.5 KB staging buffer only (4 blocks/CU by LDS).
// __launch_bounds__(256,3): VGPR cap ~170 (natural ~150) -> 3 waves/EU, NO spill.
// Heads from accumulator registers via deterministic 2-stage LDS reduce (3 heads/chunk).
__global__ __launch_bounds__(256, 3) void k_conv(
    FeatPtrs fp, const float* __restrict__ wT,
    const float* __restrict__ convb, const float* __restrict__ headw,
    const float* __restrict__ headb, float* __restrict__ scores,
    float* __restrict__ deltas) {
    __shared__ float sm[9616];  // conv: patch[4][10][10] @0, w[9216] @400; head: part[32][196]
    const int tid = threadIdx.x;
    const int cg = tid >> 3, pg = tid & 7, co0 = cg << 3;

    // level lookup
    const int bid = blockIdx.x;
    int l = 0;
#pragma unroll
    for (int q = 1; q < 5; q++) if (bid >= cv_boff[q]) l = q;
    const int H = c_W[l], W = H;
    const int soff = c_soff[l];
    const float* __restrict__ in = fp.p[l];
    const int t = bid - cv_boff[l];
    const int tilesx = (W + 7) >> 3;
    const int tx = t % tilesx, ty = t / tilesx;
    const int x0 = tx * 8, y0 = ty * 8;
    const int HW = H * W;

    float acc[8][8];
#pragma unroll
    for (int r = 0; r < 8; r++)
#pragma unroll
        for (int c = 0; c < 8; c++) acc[r][c] = 0.f;

    for (int cc0 = 0; cc0 < 256; cc0 += 4) {
        __syncthreads();
        // patch staging (scalar, bounds-checked zero-fill)
        for (int e = tid; e < 400; e += 256) {
            int ci = e / 100, rr = e % 100, py = rr / 10, px = rr % 10;
            int gy = y0 - 1 + py, gx = x0 - 1 + px;
            float v = 0.f;
            if (gy >= 0 && gy < H && gx >= 0 && gx < W)
                v = in[(cc0 + ci) * HW + gy * W + gx];
            sm[e] = v;
        }
        // weight staging, vectorized float4 (wT 16B-aligned; sm+400 = 1600B offset, 16B-aligned)
        {
            const float4* __restrict__ wsrc4 = (const float4*)(wT + (size_t)cc0 * 2304);
            float4* smw4 = (float4*)(sm + 400);
            for (int e = tid; e < 2304; e += 256) smw4[e] = wsrc4[e];
        }
        __syncthreads();
#pragma unroll
        for (int ci = 0; ci < 4; ci++) {
#pragma unroll
            for (int ky = 0; ky < 3; ky++) {
                float in10[10];
                int prow = (ci * 10 + pg + ky) * 10;
#pragma unroll
                for (int q = 0; q < 10; q++) in10[q] = sm[prow + q];
#pragma unroll
                for (int kx = 0; kx < 3; kx++) {
                    float w8[8];
                    int wb = 400 + ((ci * 3 + ky) * 3 + kx) * 256 + co0;
#pragma unroll
                    for (int r = 0; r < 8; r++) w8[r] = sm[wb + r];
#pragma unroll
                    for (int r = 0; r < 8; r++)
#pragma unroll
                        for (int c = 0; c < 8; c++)
                            acc[r][c] = fmaf(w8[r], in10[c + kx], acc[r][c]);
                }
            }
        }
    }
    // bias + relu in registers: acc becomes t
    {
        float bias[8];
#pragma unroll
        for (int r = 0; r < 8; r++) bias[r] = convb[co0 + r];
#pragma unroll
        for (int r = 0; r < 8; r++)
#pragma unroll
            for (int c = 0; c < 8; c++) {
                float tv = acc[r][c] + bias[r];
                acc[r][c] = tv > 0.f ? tv : 0.f;
            }
    }
    // heads: 15 heads in chunks of 3; per-thread partial over its 8 co,
    // then deterministic 32-way tree over cg in LDS. part layout: [cg][px*3+h'] pad 196.
    for (int hc = 0; hc < 15; hc += 3) {
        float hw3[3][8];
#pragma unroll
        for (int h3 = 0; h3 < 3; h3++)
#pragma unroll
            for (int r = 0; r < 8; r++)
                hw3[h3][r] = headw[(hc + h3) * 256 + co0 + r];
        float part[3][8];
#pragma unroll
        for (int h3 = 0; h3 < 3; h3++)
#pragma unroll
            for (int c = 0; c < 8; c++) part[h3][c] = 0.f;
#pragma unroll
        for (int r = 0; r < 8; r++)
#pragma unroll
            for (int c = 0; c < 8; c++) {
                float tv = acc[r][c];
#pragma unroll
                for (int h3 = 0; h3 < 3; h3++)
                    part[h3][c] = fmaf(hw3[h3][r], tv, part[h3][c]);
            }
        __syncthreads();  // previous chunk's reads (or conv phase) done
        int base = cg * 196 + pg * 24;
#pragma unroll
        for (int c = 0; c < 8; c++)
#pragma unroll
            for (int h3 = 0; h3 < 3; h3++)
                sm[base + c * 3 + h3] = part[h3][c];
        __syncthreads();
        if (tid < 192) {
            int px = tid / 3, h3 = tid % 3;
            int h = hc + h3;
            float sum = 0.f;
#pragma unroll
            for (int g = 0; g < 32; g++) sum += sm[g * 196 + tid];
            sum += headb[h];
            int row = px >> 3, col = px & 7;
            int gy = y0 + row, gx = x0 + col;
            if (gy < H && gx < W) {
                int pix = gy * W + gx;
                if (h < 3) {
                    scores[soff + pix * 3 + h] = sum;
                } else {
                    int ch = h - 3;
                    deltas[((size_t)(soff + pix * 3 + (ch >> 2))) * 4 + (ch & 3)] = sum;
                }
            }
        }
    }
}

// ---------------- kernel 3: per-level exact top-k (radix select) ----------------
// Writes sort keys directly: key = (~flip(score) << 32) | (level<<24 | idx)
__global__ __launch_bounds__(1024) void k_topk(
    const float* __restrict__ scores, u64* __restrict__ key) {
    const int l = blockIdx.x;
    const int Nl = c_Nl[l], off = c_soff[l], k = c_k[l];
    const int base = l * 1000;
    const int tid = threadIdx.x;
    const u32 lshift = (u32)l << 24;
    __shared__ u32 hist[256];
    __shared__ u32 sh_prefix, sh_m, sh_sel, sh_tie;
    __shared__ u32 tiebuf[2048];
    if (tid == 0) { sh_sel = 0; sh_tie = 0; }
    __syncthreads();

    if (k == Nl) {  // take everything (level 4)
        for (int i = tid; i < Nl; i += 1024) {
            u32 p = atomicAdd(&sh_sel, 1u);
            u32 k32 = flipf(scores[off + i]);
            key[base + p] = ((u64)(~k32) << 32) | (u64)(lshift | (u32)i);
        }
        return;
    }
    u32 prefix = 0, m = (u32)k;
    for (int p = 0; p < 4; p++) {
        int shift = 24 - 8 * p;
        for (int b = tid; b < 256; b += 1024) hist[b] = 0;
        __syncthreads();
        for (int i = tid; i < Nl; i += 1024) {
            u32 k32 = flipf(scores[off + i]);
            if (p == 0 || (k32 >> (shift + 8)) == prefix)
                atomicAdd(&hist[(k32 >> shift) & 255u], 1u);
        }
        __syncthreads();
        if (tid == 0) {
            u32 cum = 0;
            for (int b = 255; b >= 0; --b) {
                u32 c = hist[b];
                if (cum + c >= m) { sh_prefix = (prefix << 8) | (u32)b; sh_m = m - cum; break; }
                cum += c;
            }
        }
        __syncthreads();
        prefix = sh_prefix; m = sh_m;
        __syncthreads();
    }
    // compact: strictly greater -> selected; equal -> tie list
    for (int i = tid; i < Nl; i += 1024) {
        u32 k32 = flipf(scores[off + i]);
        if (k32 > prefix) {
            u32 p = atomicAdd(&sh_sel, 1u);
            key[base + p] = ((u64)(~k32) << 32) | (u64)(lshift | (u32)i);
        } else if (k32 == prefix) {
            u32 t = atomicAdd(&sh_tie, 1u);
            if (t < 2048u) tiebuf[t] = (u32)i;
        }
    }
    __syncthreads();
    u32 nsel = sh_sel;
    u32 ntie = sh_tie; if (ntie > 2048u) ntie = 2048u;
    if (ntie != m) {  // need m smallest indices among ties
        for (u32 j = tid; j < 2048; j += 1024) if (j >= ntie) tiebuf[j] = 0xFFFFFFFFu;
        __syncthreads();
        for (u32 ksz = 2; ksz <= 2048; ksz <<= 1) {
            for (u32 jj = ksz >> 1; jj > 0; jj >>= 1) {
                for (u32 i2 = tid; i2 < 2048; i2 += 1024) {
                    u32 ixj = i2 ^ jj;
                    if (ixj > i2) {
                        u32 a = tiebuf[i2], b = tiebuf[ixj];
                        bool up = ((i2 & ksz) == 0);
                        if ((a > b) == up) { tiebuf[i2] = b; tiebuf[ixj] = a; }
                    }
                }
                __syncthreads();
            }
        }
    }
    for (u32 j = tid; j < m; j += 1024)
        key[base + nsel + j] = ((u64)(~prefix) << 32) | (u64)(lshift | tiebuf[j]);
}

// ---------------- kernel 4: global bitonic sort + inline decode ----------------
__global__ __launch_bounds__(1024) void k_sort(
    const u64* __restrict__ key, const float* __restrict__ deltas, DecParams P,
    float* __restrict__ sboxes, float* __restrict__ sob, u32* __restrict__ svalid) {
    __shared__ u64 sk[8192];
    const int tid = threadIdx.x;
    for (int i = tid; i < 8192; i += 1024) sk[i] = (i < NCAND) ? key[i] : ~0ull;
    __syncthreads();
    for (u32 ksz = 2; ksz <= 8192; ksz <<= 1) {
        for (u32 j = ksz >> 1; j > 0; j >>= 1) {
            for (u32 i = tid; i < 8192; i += 1024) {
                u32 ixj = i ^ j;
                if (ixj > i) {
                    u64 a = sk[i], b = sk[ixj];
                    bool up = ((i & ksz) == 0);
                    if ((a > b) == up) { sk[i] = b; sk[ixj] = a; }
                }
            }
            __syncthreads();
        }
    }
    const float CLAMP = 4.135166556742356f;  // log(1000/16)
    for (int s = tid; s < NCAND; s += 1024) {
        u32 info = (u32)sk[s];
        int l = info >> 24, idx = info & 0xFFFFFF;
        int W = c_W[l], st = c_stride[l];
        int a = idx % 3, pix = idx / 3;
        int x = pix % W, y = pix / W;
        float ax1 = x * st + P.b[l][a][0];
        float ay1 = y * st + P.b[l][a][1];
        float ax2 = x * st + P.b[l][a][2];
        float ay2 = y * st + P.b[l][a][3];
        float w_ = ax2 - ax1, h_ = ay2 - ay1;
        float cx = ax1 + 0.5f * w_, cy = ay1 + 0.5f * h_;
        const float* d = deltas + ((size_t)(c_soff[l] + idx)) * 4;
        float dx = d[0], dy = d[1];
        float dw = fminf(d[2], CLAMP), dh = fminf(d[3], CLAMP);
        float pcx = dx * w_ + cx, pcy = dy * h_ + cy;
        float pw = expf(dw) * w_, ph = expf(dh) * h_;
        float x1 = pcx - 0.5f * pw, y1 = pcy - 0.5f * ph;
        float x2 = pcx + 0.5f * pw, y2 = pcy + 0.5f * ph;
        x1 = fminf(fmaxf(x1, 0.f), 800.f); y1 = fminf(fmaxf(y1, 0.f), 800.f);
        x2 = fminf(fmaxf(x2, 0.f), 800.f); y2 = fminf(fmaxf(y2, 0.f), 800.f);
        u32 vv = (x2 - x1 >= 0.001f && y2 - y1 >= 0.001f) ? 1u : 0u;
        float offv = (float)l * 801.0f;
        sboxes[s * 4 + 0] = x1; sboxes[s * 4 + 1] = y1;
        sboxes[s * 4 + 2] = x2; sboxes[s * 4 + 3] = y2;
        sob[s * 4 + 0] = x1 + offv; sob[s * 4 + 1] = y1 + offv;
        sob[s * 4 + 2] = x2 + offv; sob[s * 4 + 3] = y2 + offv;
        svalid[s] = vv;
    }
}

// ---------------- kernel 5: IoU suppression bitmask ----------------
__global__ __launch_bounds__(256) void k_mask(
    const float* __restrict__ sob, u64* __restrict__ mask) {
    int gid = blockIdx.x * 256 + threadIdx.x;
    const int total = NCAND * WORDS;
    if (gid >= total) return;
    int i = gid / WORDS, w = gid - i * WORDS;
    float bx1 = sob[i * 4], by1 = sob[i * 4 + 1], bx2 = sob[i * 4 + 2], by2 = sob[i * 4 + 3];
    float ai = (bx2 - bx1) * (by2 - by1);
    u64 bits = 0;
    int j0 = w * 64;
    for (int b = 0; b < 64; b++) {
        int j = j0 + b;
        if (j < NCAND && j > i) {
            float cx1 = sob[j * 4], cy1 = sob[j * 4 + 1], cx2 = sob[j * 4 + 2], cy2 = sob[j * 4 + 3];
            float lt0 = fmaxf(bx1, cx1), lt1 = fmaxf(by1, cy1);
            float rb0 = fminf(bx2, cx2), rb1 = fminf(by2, cy2);
            float ww = fmaxf(rb0 - lt0, 0.f), hh = fmaxf(rb1 - lt1, 0.f);
            float inter = ww * hh;
            float aj = (cx2 - cx1) * (cy2 - cy1);
            float u = ai + aj - inter;
            float iou = inter / u;           // 0/0 -> NaN -> no suppression (matches ref)
            if (iou > 0.7f) bits |= (1ull << b);
        }
    }
    mask[(size_t)i * WORDS + w] = bits;
}

// ---------------- kernel 6: tiled greedy NMS scan (single block) ----------------
__global__ __launch_bounds__(256) void k_scan(
    const u64* __restrict__ mask, const u32* __restrict__ svalid,
    u64* __restrict__ keepg) {
    __shared__ u64 keep[WORDS];
    __shared__ u32 ormL[WORDS], ormH[WORDS];
    const int tid = threadIdx.x;
    if (tid < WORDS) {
        u64 w0 = 0;
        for (int b = 0; b < 64; b++) {
            int idx = tid * 64 + b;
            if (idx < NCAND && svalid[idx]) w0 |= (1ull << b);
        }
        keep[tid] = w0; ormL[tid] = 0; ormH[tid] = 0;
    }
    __syncthreads();
    for (int t = 0; t < WORDS; t++) {
        if (tid < 64) {  // wave 0: serial intra-tile resolve on the diagonal word
            int row = t * 64 + tid;
            u64 d = (row < NCAND) ? mask[(size_t)row * WORDS + t] : 0ull;
            u32 dlo = (u32)d, dhi = (u32)(d >> 32);
            u64 cur = keep[t];
            u64 pending = cur;
            while (pending) {
                int b = __builtin_ctzll(pending);
                pending &= pending - 1;
                u64 mb = ((u64)__shfl(dhi, b, 64) << 32) | (u64)__shfl(dlo, b, 64);
                cur &= ~mb;       // row b is alive (pending only holds survivors)
                pending &= ~mb;   // skip rows it just suppressed
            }
            if (tid == 0) keep[t] = cur;
        }
        __syncthreads();
        u64 kw = keep[t];
        int nW = WORDS - 1 - t;
        for (int task = tid; task < 64 * nW; task += 256) {
            int r = task / nW, w = t + 1 + (task - r * nW);
            if ((kw >> r) & 1ull) {
                u64 mrow = mask[(size_t)(t * 64 + r) * WORDS + w];
                if (mrow) {
                    atomicOr(&ormL[w], (u32)mrow);
                    atomicOr(&ormH[w], (u32)(mrow >> 32));
                }
            }
        }
        __syncthreads();
        if (tid > t && tid < WORDS) {
            keep[tid] &= ~(((u64)ormH[tid] << 32) | (u64)ormL[tid]);
            ormL[tid] = 0; ormH[tid] = 0;
        }
        __syncthreads();
    }
    if (tid < WORDS) keepg[tid] = keep[tid];
}

// ---------------- kernel 7: final gather (kept first, then suppressed in index order) ----------------
__global__ __launch_bounds__(1024) void k_out(
    const u64* __restrict__ keepg, const float* __restrict__ sboxes,
    float* __restrict__ out) {
    __shared__ u32 sc[1024];
    __shared__ u64 kw[WORDS];
    const int tid = threadIdx.x;
    if (tid < WORDS) kw[tid] = keepg[tid];
    __syncthreads();
    const int i0 = tid * 5;
    u32 cnt = 0;
    for (int e = 0; e < 5; e++) {
        int i = i0 + e;
        if (i < NCAND) cnt += (u32)((kw[i >> 6] >> (i & 63)) & 1ull);
    }
    sc[tid] = cnt;
    __syncthreads();
    for (int off = 1; off < 1024; off <<= 1) {
        u32 v = (tid >= off) ? sc[tid - off] : 0;
        __syncthreads();
        sc[tid] += v;
        __syncthreads();
    }
    u32 incl = sc[tid];
    u32 total = sc[1023];
    u32 kr = incl - cnt;  // kept before my first element
    for (int e = 0; e < 5; e++) {
        int i = i0 + e;
        if (i < NCAND) {
            bool kp = (kw[i >> 6] >> (i & 63)) & 1ull;
            if (kp) {
                if (kr < 1000u) {
                    out[kr * 4 + 0] = sboxes[i * 4 + 0];
                    out[kr * 4 + 1] = sboxes[i * 4 + 1];
                    out[kr * 4 + 2] = sboxes[i * 4 + 2];
                    out[kr * 4 + 3] = sboxes[i * 4 + 3];
                }
                kr++;
            } else {
                u32 slot = total + (u32)i - kr;
                if (slot < 1000u) {
                    out[slot * 4 + 0] = sboxes[i * 4 + 0];
                    out[slot * 4 + 1] = sboxes[i * 4 + 1];
                    out[slot * 4 + 2] = sboxes[i * 4 + 2];
                    out[slot * 4 + 3] = sboxes[i * 4 + 3];
                }
            }
        }
    }
}

// ---------------- host ----------------
extern "C" void kernel_launch(void* const* d_in, const int* in_sizes, int n_in,
                              void* d_out, int out_size, void* d_ws, size_t ws_size,
                              hipStream_t stream) {
    (void)in_sizes; (void)n_in; (void)out_size; (void)ws_size;
    FeatPtrs fp;
    for (int i = 0; i < 5; i++) fp.p[i] = (const float*)d_in[i];
    const float* conv_w = (const float*)d_in[5];
    const float* conv_b = (const float*)d_in[6];
    const float* cls_w  = (const float*)d_in[7];
    const float* cls_b  = (const float*)d_in[8];
    const float* bbox_w = (const float*)d_in[9];
    const float* bbox_b = (const float*)d_in[10];

    char* ws = (char*)d_ws;
    float* wT     = (float*)(ws + OFF_WT);
    float* headw  = (float*)(ws + OFF_HEADW);
    float* headb  = (float*)(ws + OFF_HEADB);
    float* scores = (float*)(ws + OFF_SCORES);
    float* deltas = (float*)(ws + OFF_DELTAS);
    u64*   key    = (u64*)(ws + OFF_KEY);
    float* sboxes = (float*)(ws + OFF_SBOX);
    float* sob    = (float*)(ws + OFF_SOB);
    u32*   svalid = (u32*)(ws + OFF_SVAL);
    u64*   maskp  = (u64*)(ws + OFF_MASK);
    u64*   keepg  = (u64*)(ws + OFF_KEEP);

    k_prep<<<2304, 256, 0, stream>>>(conv_w, cls_w, cls_b, bbox_w, bbox_b, wT, headw, headb);

    // one launch for all 5 levels: 625+169+49+16+4 = 863 tiles
    k_conv<<<863, 256, 0, stream>>>(fp, wT, conv_b, headw, headb, scores, deltas);

    k_topk<<<5, 1024, 0, stream>>>(scores, key);

    DecParams dp;
    {
        const double sz[5] = {32.0, 64.0, 128.0, 256.0, 512.0};
        const double rt[3] = {0.5, 1.0, 2.0};
        for (int l = 0; l < 5; l++)
            for (int a = 0; a < 3; a++) {
                double hr = sqrt(rt[a]);
                double wr = 1.0 / hr;
                double w = wr * sz[l], h = hr * sz[l];
                dp.b[l][a][0] = (float)nearbyint(-w / 2.0);
                dp.b[l][a][1] = (float)nearbyint(-h / 2.0);
                dp.b[l][a][2] = (float)nearbyint(w / 2.0);
                dp.b[l][a][3] = (float)nearbyint(h / 2.0);
            }
    }
    k_sort<<<1, 1024, 0, stream>>>(key, deltas, dp, sboxes, sob, svalid);
    k_mask<<<(NCAND * WORDS + 255) / 256, 256, 0, stream>>>(sob, maskp);
    k_scan<<<1, 256, 0, stream>>>(maskp, svalid, keepg);
    k_out<<<1, 1024, 0, stream>>>(keepg, sboxes, (float*)d_out);
}

// Round 4
// 1719.701 us; speedup vs baseline: 1.8750x; 1.3983x over previous
//
#include <hip/hip_runtime.h>
#include <cmath>

typedef unsigned int u32;
typedef unsigned long long u64;

#define NCAND 4507
#define WORDS 71              // ceil(4507/64)
#define ROWS_AL (WORDS * 64)  // 4544
#define TOTS 159882           // total scores across levels

__constant__ int c_W[5]      = {200, 100, 50, 25, 13};
__constant__ int c_stride[5] = {4, 8, 16, 32, 61};
__constant__ int c_Nl[5]     = {120000, 30000, 7500, 1875, 507};
__constant__ int c_soff[5]   = {0, 120000, 150000, 157500, 159375};
__constant__ int c_k[5]      = {1000, 1000, 1000, 1000, 507};

// unified conv grid: tiles per level (8x8 px tiles): 625,169,49,16,4
__constant__ int cv_boff[6]  = {0, 625, 794, 843, 859, 863};

struct DecParams { float b[5][3][4]; };
struct FeatPtrs { const float* p[5]; };

__device__ __forceinline__ u32 flipf(float f) {
    u32 u = __float_as_uint(f);
    return (u & 0x80000000u) ? ~u : (u | 0x80000000u);
}

// ---------------- workspace layout ----------------
constexpr size_t AL(size_t x) { return (x + 255) & ~(size_t)255; }
constexpr size_t OFF_WT     = 0;                                   // 589824 f
constexpr size_t OFF_HEADW  = AL(OFF_WT + 589824 * 4);             // 15*256 f
constexpr size_t OFF_HEADB  = AL(OFF_HEADW + 3840 * 4);            // 15 f
constexpr size_t OFF_SCORES = AL(OFF_HEADB + 64);                  // TOTS f
constexpr size_t OFF_DELTAS = AL(OFF_SCORES + (size_t)TOTS * 4);   // TOTS*4 f
constexpr size_t OFF_KEY    = AL(OFF_DELTAS + (size_t)TOTS * 16);  // NCAND u64
constexpr size_t OFF_SBOX   = AL(OFF_KEY + (size_t)NCAND * 8);     // NCAND*4 f
constexpr size_t OFF_SOB    = AL(OFF_SBOX + (size_t)NCAND * 16);   // NCAND*4 f
constexpr size_t OFF_SVAL   = AL(OFF_SOB + (size_t)NCAND * 16);    // NCAND u32
constexpr size_t OFF_MASK   = AL(OFF_SVAL + (size_t)NCAND * 4);    // ROWS_AL*WORDS u64
constexpr size_t OFF_KEEP   = AL(OFF_MASK + (size_t)ROWS_AL * WORDS * 8); // WORDS u64

// ---------------- kernel 1: weight prep ----------------
// wT[ci][ky][kx][co]  from conv_w[co][ci][ky][kx]; combined head weights/bias.
__global__ __launch_bounds__(256) void k_prep(
    const float* __restrict__ cw, const float* __restrict__ clsw,
    const float* __restrict__ clsb, const float* __restrict__ bw,
    const float* __restrict__ bb, float* __restrict__ wT,
    float* __restrict__ headw, float* __restrict__ headb) {
    int i = blockIdx.x * 256 + threadIdx.x;
    if (i < 589824) {
        int co = i & 255, r = i >> 8;
        int kx = r % 3, ky = (r / 3) % 3, ci = r / 9;
        wT[i] = cw[(((co << 8) + ci) * 3 + ky) * 3 + kx];
    }
    if (i < 3840) {
        int h = i >> 8, ci = i & 255;
        headw[i] = (h < 3) ? clsw[h * 256 + ci] : bw[(h - 3) * 256 + ci];
    }
    if (i < 15) headb[i] = (i < 3) ? clsb[i] : bb[i - 3];
}

// ---------------- kernel 2: fused conv3x3+ReLU + 1x1 heads, ALL LEVELS ----------------
// Block: 256 threads -> 8x8 pixel tile, all 256 output channels.
// Thread (cg,pg): 8 co x 8 px register micro-tile.
// LDS: single 38.5 KB staging buffer (4 blocks/CU by LDS).
// NOTE: no min-waves arg on __launch_bounds__ — (256,4) capped VGPR at 64 and
// (256,3) at 84 on this compiler (cap ~= 512/(2N)), both spilling ~GBs to
// scratch (r2: WRITE_SIZE 4.7 GB, r3: 1.7 GB). Natural allocation (r1: 124
// VGPR) is spill-free; VGPR ~150 -> 3 waves/EU anyway.
__global__ __launch_bounds__(256) void k_conv(
    FeatPtrs fp, const float* __restrict__ wT,
    const float* __restrict__ convb, const float* __restrict__ headw,
    const float* __restrict__ headb, float* __restrict__ scores,
    float* __restrict__ deltas) {
    __shared__ float sm[9616];  // conv: patch[4][10][10] @0, w[9216] @400; head: part[32][196]
    const int tid = threadIdx.x;
    const int cg = tid >> 3, pg = tid & 7, co0 = cg << 3;

    // level lookup
    const int bid = blockIdx.x;
    int l = 0;
#pragma unroll
    for (int q = 1; q < 5; q++) if (bid >= cv_boff[q]) l = q;
    const int H = c_W[l], W = H;
    const int soff = c_soff[l];
    const float* __restrict__ in = fp.p[l];
    const int t = bid - cv_boff[l];
    const int tilesx = (W + 7) >> 3;
    const int tx = t % tilesx, ty = t / tilesx;
    const int x0 = tx * 8, y0 = ty * 8;
    const int HW = H * W;

    float acc[8][8];
#pragma unroll
    for (int r = 0; r < 8; r++)
#pragma unroll
        for (int c = 0; c < 8; c++) acc[r][c] = 0.f;

    for (int cc0 = 0; cc0 < 256; cc0 += 4) {
        __syncthreads();
        // patch staging (scalar, bounds-checked zero-fill)
        for (int e = tid; e < 400; e += 256) {
            int ci = e / 100, rr = e % 100, py = rr / 10, px = rr % 10;
            int gy = y0 - 1 + py, gx = x0 - 1 + px;
            float v = 0.f;
            if (gy >= 0 && gy < H && gx >= 0 && gx < W)
                v = in[(cc0 + ci) * HW + gy * W + gx];
            sm[e] = v;
        }
        // weight staging, vectorized float4 (wT 16B-aligned; sm+400 = 1600B offset, 16B-aligned)
        {
            const float4* __restrict__ wsrc4 = (const float4*)(wT + (size_t)cc0 * 2304);
            float4* smw4 = (float4*)(sm + 400);
            for (int e = tid; e < 2304; e += 256) smw4[e] = wsrc4[e];
        }
        __syncthreads();
#pragma unroll
        for (int ci = 0; ci < 4; ci++) {
#pragma unroll
            for (int ky = 0; ky < 3; ky++) {
                float in10[10];
                int prow = (ci * 10 + pg + ky) * 10;
#pragma unroll
                for (int q = 0; q < 10; q++) in10[q] = sm[prow + q];
#pragma unroll
                for (int kx = 0; kx < 3; kx++) {
                    float w8[8];
                    int wb = 400 + ((ci * 3 + ky) * 3 + kx) * 256 + co0;
#pragma unroll
                    for (int r = 0; r < 8; r++) w8[r] = sm[wb + r];
#pragma unroll
                    for (int r = 0; r < 8; r++)
#pragma unroll
                        for (int c = 0; c < 8; c++)
                            acc[r][c] = fmaf(w8[r], in10[c + kx], acc[r][c]);
                }
            }
        }
    }
    // bias + relu in registers: acc becomes t
    {
        float bias[8];
#pragma unroll
        for (int r = 0; r < 8; r++) bias[r] = convb[co0 + r];
#pragma unroll
        for (int r = 0; r < 8; r++)
#pragma unroll
            for (int c = 0; c < 8; c++) {
                float tv = acc[r][c] + bias[r];
                acc[r][c] = tv > 0.f ? tv : 0.f;
            }
    }
    // heads: 15 heads in chunks of 3; per-thread partial over its 8 co,
    // then deterministic 32-way tree over cg in LDS. part layout: [cg][px*3+h'] pad 196.
    for (int hc = 0; hc < 15; hc += 3) {
        float hw3[3][8];
#pragma unroll
        for (int h3 = 0; h3 < 3; h3++)
#pragma unroll
            for (int r = 0; r < 8; r++)
                hw3[h3][r] = headw[(hc + h3) * 256 + co0 + r];
        float part[3][8];
#pragma unroll
        for (int h3 = 0; h3 < 3; h3++)
#pragma unroll
            for (int c = 0; c < 8; c++) part[h3][c] = 0.f;
#pragma unroll
        for (int r = 0; r < 8; r++)
#pragma unroll
            for (int c = 0; c < 8; c++) {
                float tv = acc[r][c];
#pragma unroll
                for (int h3 = 0; h3 < 3; h3++)
                    part[h3][c] = fmaf(hw3[h3][r], tv, part[h3][c]);
            }
        __syncthreads();  // previous chunk's reads (or conv phase) done
        int base = cg * 196 + pg * 24;
#pragma unroll
        for (int c = 0; c < 8; c++)
#pragma unroll
            for (int h3 = 0; h3 < 3; h3++)
                sm[base + c * 3 + h3] = part[h3][c];
        __syncthreads();
        if (tid < 192) {
            int px = tid / 3, h3 = tid % 3;
            int h = hc + h3;
            float sum = 0.f;
#pragma unroll
            for (int g = 0; g < 32; g++) sum += sm[g * 196 + tid];
            sum += headb[h];
            int row = px >> 3, col = px & 7;
            int gy = y0 + row, gx = x0 + col;
            if (gy < H && gx < W) {
                int pix = gy * W + gx;
                if (h < 3) {
                    scores[soff + pix * 3 + h] = sum;
                } else {
                    int ch = h - 3;
                    deltas[((size_t)(soff + pix * 3 + (ch >> 2))) * 4 + (ch & 3)] = sum;
                }
            }
        }
    }
}

// ---------------- kernel 3: per-level exact top-k (radix select) ----------------
// Writes sort keys directly: key = (~flip(score) << 32) | (level<<24 | idx)
__global__ __launch_bounds__(1024) void k_topk(
    const float* __restrict__ scores, u64* __restrict__ key) {
    const int l = blockIdx.x;
    const int Nl = c_Nl[l], off = c_soff[l], k = c_k[l];
    const int base = l * 1000;
    const int tid = threadIdx.x;
    const u32 lshift = (u32)l << 24;
    __shared__ u32 hist[256];
    __shared__ u32 sh_prefix, sh_m, sh_sel, sh_tie;
    __shared__ u32 tiebuf[2048];
    if (tid == 0) { sh_sel = 0; sh_tie = 0; }
    __syncthreads();

    if (k == Nl) {  // take everything (level 4)
        for (int i = tid; i < Nl; i += 1024) {
            u32 p = atomicAdd(&sh_sel, 1u);
            u32 k32 = flipf(scores[off + i]);
            key[base + p] = ((u64)(~k32) << 32) | (u64)(lshift | (u32)i);
        }
        return;
    }
    u32 prefix = 0, m = (u32)k;
    for (int p = 0; p < 4; p++) {
        int shift = 24 - 8 * p;
        for (int b = tid; b < 256; b += 1024) hist[b] = 0;
        __syncthreads();
        for (int i = tid; i < Nl; i += 1024) {
            u32 k32 = flipf(scores[off + i]);
            if (p == 0 || (k32 >> (shift + 8)) == prefix)
                atomicAdd(&hist[(k32 >> shift) & 255u], 1u);
        }
        __syncthreads();
        if (tid == 0) {
            u32 cum = 0;
            for (int b = 255; b >= 0; --b) {
                u32 c = hist[b];
                if (cum + c >= m) { sh_prefix = (prefix << 8) | (u32)b; sh_m = m - cum; break; }
                cum += c;
            }
        }
        __syncthreads();
        prefix = sh_prefix; m = sh_m;
        __syncthreads();
    }
    // compact: strictly greater -> selected; equal -> tie list
    for (int i = tid; i < Nl; i += 1024) {
        u32 k32 = flipf(scores[off + i]);
        if (k32 > prefix) {
            u32 p = atomicAdd(&sh_sel, 1u);
            key[base + p] = ((u64)(~k32) << 32) | (u64)(lshift | (u32)i);
        } else if (k32 == prefix) {
            u32 t = atomicAdd(&sh_tie, 1u);
            if (t < 2048u) tiebuf[t] = (u32)i;
        }
    }
    __syncthreads();
    u32 nsel = sh_sel;
    u32 ntie = sh_tie; if (ntie > 2048u) ntie = 2048u;
    if (ntie != m) {  // need m smallest indices among ties
        for (u32 j = tid; j < 2048; j += 1024) if (j >= ntie) tiebuf[j] = 0xFFFFFFFFu;
        __syncthreads();
        for (u32 ksz = 2; ksz <= 2048; ksz <<= 1) {
            for (u32 jj = ksz >> 1; jj > 0; jj >>= 1) {
                for (u32 i2 = tid; i2 < 2048; i2 += 1024) {
                    u32 ixj = i2 ^ jj;
                    if (ixj > i2) {
                        u32 a = tiebuf[i2], b = tiebuf[ixj];
                        bool up = ((i2 & ksz) == 0);
                        if ((a > b) == up) { tiebuf[i2] = b; tiebuf[ixj] = a; }
                    }
                }
                __syncthreads();
            }
        }
    }
    for (u32 j = tid; j < m; j += 1024)
        key[base + nsel + j] = ((u64)(~prefix) << 32) | (u64)(lshift | tiebuf[j]);
}

// ---------------- kernel 4: global bitonic sort + inline decode ----------------
__global__ __launch_bounds__(1024) void k_sort(
    const u64* __restrict__ key, const float* __restrict__ deltas, DecParams P,
    float* __restrict__ sboxes, float* __restrict__ sob, u32* __restrict__ svalid) {
    __shared__ u64 sk[8192];
    const int tid = threadIdx.x;
    for (int i = tid; i < 8192; i += 1024) sk[i] = (i < NCAND) ? key[i] : ~0ull;
    __syncthreads();
    for (u32 ksz = 2; ksz <= 8192; ksz <<= 1) {
        for (u32 j = ksz >> 1; j > 0; j >>= 1) {
            for (u32 i = tid; i < 8192; i += 1024) {
                u32 ixj = i ^ j;
                if (ixj > i) {
                    u64 a = sk[i], b = sk[ixj];
                    bool up = ((i & ksz) == 0);
                    if ((a > b) == up) { sk[i] = b; sk[ixj] = a; }
                }
            }
            __syncthreads();
        }
    }
    const float CLAMP = 4.135166556742356f;  // log(1000/16)
    for (int s = tid; s < NCAND; s += 1024) {
        u32 info = (u32)sk[s];
        int l = info >> 24, idx = info & 0xFFFFFF;
        int W = c_W[l], st = c_stride[l];
        int a = idx % 3, pix = idx / 3;
        int x = pix % W, y = pix / W;
        float ax1 = x * st + P.b[l][a][0];
        float ay1 = y * st + P.b[l][a][1];
        float ax2 = x * st + P.b[l][a][2];
        float ay2 = y * st + P.b[l][a][3];
        float w_ = ax2 - ax1, h_ = ay2 - ay1;
        float cx = ax1 + 0.5f * w_, cy = ay1 + 0.5f * h_;
        const float* d = deltas + ((size_t)(c_soff[l] + idx)) * 4;
        float dx = d[0], dy = d[1];
        float dw = fminf(d[2], CLAMP), dh = fminf(d[3], CLAMP);
        float pcx = dx * w_ + cx, pcy = dy * h_ + cy;
        float pw = expf(dw) * w_, ph = expf(dh) * h_;
        float x1 = pcx - 0.5f * pw, y1 = pcy - 0.5f * ph;
        float x2 = pcx + 0.5f * pw, y2 = pcy + 0.5f * ph;
        x1 = fminf(fmaxf(x1, 0.f), 800.f); y1 = fminf(fmaxf(y1, 0.f), 800.f);
        x2 = fminf(fmaxf(x2, 0.f), 800.f); y2 = fminf(fmaxf(y2, 0.f), 800.f);
        u32 vv = (x2 - x1 >= 0.001f && y2 - y1 >= 0.001f) ? 1u : 0u;
        float offv = (float)l * 801.0f;
        sboxes[s * 4 + 0] = x1; sboxes[s * 4 + 1] = y1;
        sboxes[s * 4 + 2] = x2; sboxes[s * 4 + 3] = y2;
        sob[s * 4 + 0] = x1 + offv; sob[s * 4 + 1] = y1 + offv;
        sob[s * 4 + 2] = x2 + offv; sob[s * 4 + 3] = y2 + offv;
        svalid[s] = vv;
    }
}

// ---------------- kernel 5: IoU suppression bitmask ----------------
__global__ __launch_bounds__(256) void k_mask(
    const float* __restrict__ sob, u64* __restrict__ mask) {
    int gid = blockIdx.x * 256 + threadIdx.x;
    const int total = NCAND * WORDS;
    if (gid >= total) return;
    int i = gid / WORDS, w = gid - i * WORDS;
    float bx1 = sob[i * 4], by1 = sob[i * 4 + 1], bx2 = sob[i * 4 + 2], by2 = sob[i * 4 + 3];
    float ai = (bx2 - bx1) * (by2 - by1);
    u64 bits = 0;
    int j0 = w * 64;
    for (int b = 0; b < 64; b++) {
        int j = j0 + b;
        if (j < NCAND && j > i) {
            float cx1 = sob[j * 4], cy1 = sob[j * 4 + 1], cx2 = sob[j * 4 + 2], cy2 = sob[j * 4 + 3];
            float lt0 = fmaxf(bx1, cx1), lt1 = fmaxf(by1, cy1);
            float rb0 = fminf(bx2, cx2), rb1 = fminf(by2, cy2);
            float ww = fmaxf(rb0 - lt0, 0.f), hh = fmaxf(rb1 - lt1, 0.f);
            float inter = ww * hh;
            float aj = (cx2 - cx1) * (cy2 - cy1);
            float u = ai + aj - inter;
            float iou = inter / u;           // 0/0 -> NaN -> no suppression (matches ref)
            if (iou > 0.7f) bits |= (1ull << b);
        }
    }
    mask[(size_t)i * WORDS + w] = bits;
}

// ---------------- kernel 6: tiled greedy NMS scan (single block) ----------------
__global__ __launch_bounds__(256) void k_scan(
    const u64* __restrict__ mask, const u32* __restrict__ svalid,
    u64* __restrict__ keepg) {
    __shared__ u64 keep[WORDS];
    __shared__ u32 ormL[WORDS], ormH[WORDS];
    const int tid = threadIdx.x;
    if (tid < WORDS) {
        u64 w0 = 0;
        for (int b = 0; b < 64; b++) {
            int idx = tid * 64 + b;
            if (idx < NCAND && svalid[idx]) w0 |= (1ull << b);
        }
        keep[tid] = w0; ormL[tid] = 0; ormH[tid] = 0;
    }
    __syncthreads();
    for (int t = 0; t < WORDS; t++) {
        if (tid < 64) {  // wave 0: serial intra-tile resolve on the diagonal word
            int row = t * 64 + tid;
            u64 d = (row < NCAND) ? mask[(size_t)row * WORDS + t] : 0ull;
            u32 dlo = (u32)d, dhi = (u32)(d >> 32);
            u64 cur = keep[t];
            u64 pending = cur;
            while (pending) {
                int b = __builtin_ctzll(pending);
                pending &= pending - 1;
                u64 mb = ((u64)__shfl(dhi, b, 64) << 32) | (u64)__shfl(dlo, b, 64);
                cur &= ~mb;       // row b is alive (pending only holds survivors)
                pending &= ~mb;   // skip rows it just suppressed
            }
            if (tid == 0) keep[t] = cur;
        }
        __syncthreads();
        u64 kw = keep[t];
        int nW = WORDS - 1 - t;
        for (int task = tid; task < 64 * nW; task += 256) {
            int r = task / nW, w = t + 1 + (task - r * nW);
            if ((kw >> r) & 1ull) {
                u64 mrow = mask[(size_t)(t * 64 + r) * WORDS + w];
                if (mrow) {
                    atomicOr(&ormL[w], (u32)mrow);
                    atomicOr(&ormH[w], (u32)(mrow >> 32));
                }
            }
        }
        __syncthreads();
        if (tid > t && tid < WORDS) {
            keep[tid] &= ~(((u64)ormH[tid] << 32) | (u64)ormL[tid]);
            ormL[tid] = 0; ormH[tid] = 0;
        }
        __syncthreads();
    }
    if (tid < WORDS) keepg[tid] = keep[tid];
}

// ---------------- kernel 7: final gather (kept first, then suppressed in index order) ----------------
__global__ __launch_bounds__(1024) void k_out(
    const u64* __restrict__ keepg, const float* __restrict__ sboxes,
    float* __restrict__ out) {
    __shared__ u32 sc[1024];
    __shared__ u64 kw[WORDS];
    const int tid = threadIdx.x;
    if (tid < WORDS) kw[tid] = keepg[tid];
    __syncthreads();
    const int i0 = tid * 5;
    u32 cnt = 0;
    for (int e = 0; e < 5; e++) {
        int i = i0 + e;
        if (i < NCAND) cnt += (u32)((kw[i >> 6] >> (i & 63)) & 1ull);
    }
    sc[tid] = cnt;
    __syncthreads();
    for (int off = 1; off < 1024; off <<= 1) {
        u32 v = (tid >= off) ? sc[tid - off] : 0;
        __syncthreads();
        sc[tid] += v;
        __syncthreads();
    }
    u32 incl = sc[tid];
    u32 total = sc[1023];
    u32 kr = incl - cnt;  // kept before my first element
    for (int e = 0; e < 5; e++) {
        int i = i0 + e;
        if (i < NCAND) {
            bool kp = (kw[i >> 6] >> (i & 63)) & 1ull;
            if (kp) {
                if (kr < 1000u) {
                    out[kr * 4 + 0] = sboxes[i * 4 + 0];
                    out[kr * 4 + 1] = sboxes[i * 4 + 1];
                    out[kr * 4 + 2] = sboxes[i * 4 + 2];
                    out[kr * 4 + 3] = sboxes[i * 4 + 3];
                }
                kr++;
            } else {
                u32 slot = total + (u32)i - kr;
                if (slot < 1000u) {
                    out[slot * 4 + 0] = sboxes[i * 4 + 0];
                    out[slot * 4 + 1] = sboxes[i * 4 + 1];
                    out[slot * 4 + 2] = sboxes[i * 4 + 2];
                    out[slot * 4 + 3] = sboxes[i * 4 + 3];
                }
            }
        }
    }
}

// ---------------- host ----------------
extern "C" void kernel_launch(void* const* d_in, const int* in_sizes, int n_in,
                              void* d_out, int out_size, void* d_ws, size_t ws_size,
                              hipStream_t stream) {
    (void)in_sizes; (void)n_in; (void)out_size; (void)ws_size;
    FeatPtrs fp;
    for (int i = 0; i < 5; i++) fp.p[i] = (const float*)d_in[i];
    const float* conv_w = (const float*)d_in[5];
    const float* conv_b = (const float*)d_in[6];
    const float* cls_w  = (const float*)d_in[7];
    const float* cls_b  = (const float*)d_in[8];
    const float* bbox_w = (const float*)d_in[9];
    const float* bbox_b = (const float*)d_in[10];

    char* ws = (char*)d_ws;
    float* wT     = (float*)(ws + OFF_WT);
    float* headw  = (float*)(ws + OFF_HEADW);
    float* headb  = (float*)(ws + OFF_HEADB);
    float* scores = (float*)(ws + OFF_SCORES);
    float* deltas = (float*)(ws + OFF_DELTAS);
    u64*   key    = (u64*)(ws + OFF_KEY);
    float* sboxes = (float*)(ws + OFF_SBOX);
    float* sob    = (float*)(ws + OFF_SOB);
    u32*   svalid = (u32*)(ws + OFF_SVAL);
    u64*   maskp  = (u64*)(ws + OFF_MASK);
    u64*   keepg  = (u64*)(ws + OFF_KEEP);

    k_prep<<<2304, 256, 0, stream>>>(conv_w, cls_w, cls_b, bbox_w, bbox_b, wT, headw, headb);

    // one launch for all 5 levels: 625+169+49+16+4 = 863 tiles
    k_conv<<<863, 256, 0, stream>>>(fp, wT, conv_b, headw, headb, scores, deltas);

    k_topk<<<5, 1024, 0, stream>>>(scores, key);

    DecParams dp;
    {
        const double sz[5] = {32.0, 64.0, 128.0, 256.0, 512.0};
        const double rt[3] = {0.5, 1.0, 2.0};
        for (int l = 0; l < 5; l++)
            for (int a = 0; a < 3; a++) {
                double hr = sqrt(rt[a]);
                double wr = 1.0 / hr;
                double w = wr * sz[l], h = hr * sz[l];
                dp.b[l][a][0] = (float)nearbyint(-w / 2.0);
                dp.b[l][a][1] = (float)nearbyint(-h / 2.0);
                dp.b[l][a][2] = (float)nearbyint(w / 2.0);
                dp.b[l][a][3] = (float)nearbyint(h / 2.0);
            }
    }
    k_sort<<<1, 1024, 0, stream>>>(key, deltas, dp, sboxes, sob, svalid);
    k_mask<<<(NCAND * WORDS + 255) / 256, 256, 0, stream>>>(sob, maskp);
    k_scan<<<1, 256, 0, stream>>>(maskp, svalid, keepg);
    k_out<<<1, 1024, 0, stream>>>(keepg, sboxes, (float*)d_out);
}